// Round 5
// baseline (307.446 us; speedup 1.0000x reference)
//
#include <hip/hip_runtime.h>
#include <hip/hip_bf16.h>
#include <stdint.h>

typedef __attribute__((ext_vector_type(8))) __bf16 bf16x8;
typedef __attribute__((ext_vector_type(4))) float floatx4;

__device__ __forceinline__ unsigned short f2bf(float f) {
  __hip_bfloat16 h = __float2bfloat16(f);
  return __builtin_bit_cast(unsigned short, h);
}
__device__ __forceinline__ __bf16 f2b(float f) {
  return __builtin_bit_cast(__bf16, f2bf(f));
}
__device__ __forceinline__ float bf2f(unsigned short u) {
  __hip_bfloat16 h = __builtin_bit_cast(__hip_bfloat16, u);
  return __bfloat162float(h);
}
__device__ __forceinline__ bf16x8 cvt8(const float* p) {
  floatx4 a = *(const floatx4*)p;
  floatx4 b = *(const floatx4*)(p + 4);
  bf16x8 r;
#pragma unroll
  for (int i = 0; i < 4; ++i) { r[i] = f2b(a[i]); r[4 + i] = f2b(b[i]); }
  return r;
}
__device__ __forceinline__ void gload_lds16(const unsigned short* g, unsigned short* l) {
  __builtin_amdgcn_global_load_lds(
      (const __attribute__((address_space(1))) unsigned int*)g,
      (__attribute__((address_space(3))) unsigned int*)l, 16, 0, 0);
}
__device__ __forceinline__ int reg3(int t) { return t < 49 ? 0 : (t < 53 ? 1 : 2); }

#define NX 19267584
#define NQW 442368
#define NPW 147456

// ---------------------------------------------------------------------------
// Kernel 0: fp32 -> bf16 conversion of x, qkv_w, proj_w into ws.
// ---------------------------------------------------------------------------
__global__ __launch_bounds__(256) void cvt_all(
    const float* __restrict__ x, const float* __restrict__ wq,
    const float* __restrict__ wp, unsigned short* __restrict__ xb,
    unsigned short* __restrict__ wqb, unsigned short* __restrict__ wpb) {
  int i = (blockIdx.x * 256 + threadIdx.x) * 8;
  if (i < NX) {
    *(bf16x8*)(xb + i) = cvt8(x + i);
  } else if (i < NX + NQW) {
    int o = i - NX;
    *(bf16x8*)(wqb + o) = cvt8(wq + o);
  } else {
    int o = i - NX - NQW;
    *(bf16x8*)(wpb + o) = cvt8(wp + o);
  }
}

// ---------------------------------------------------------------------------
// Kernel 1: fused shift-gather + QKV GEMM, A-stationary, 2 A-frags/wave,
// A-fragments STREAMED (af[kk+1] loaded during iteration kk; only 2
// generations live after unroll -> no R3 spill). B double-buffered in LDS
// with XOR swizzle (0 conflicts), counted vmcnt(8) (4 af + 4 stage in
// flight). Grid (392, 3); each block: 128 rows x 3 tn tiles of 128 cols.
// ---------------------------------------------------------------------------
#define QSTAGE(TN, KK, BUF)                                                   \
  {                                                                           \
    _Pragma("unroll") for (int s = 0; s < 4; ++s)                             \
        gload_lds16(bq + ((size_t)(TN) * 128 + s * 8) * 384 + (KK) * 64,      \
                    &Bs[BUF][(wave * 32 + s * 8) * 64]);                      \
  }

__global__ __launch_bounds__(256, 3) void qkv_gemm(
    const unsigned short* __restrict__ xb,
    const unsigned short* __restrict__ w,
    const float* __restrict__ bias,
    unsigned short* __restrict__ qk,
    unsigned short* __restrict__ vb) {
  __shared__ unsigned short Bs[2][128 * 64];
  const int tid = threadIdx.x;
  const int wave = tid >> 6, lane = tid & 63, quad = lane >> 4, l16 = lane & 15;
  const int tm = blockIdx.x;  // 0..391 (128 rows each)
  const int tg = blockIdx.y;  // 0..2  (3 tn tiles each)

  // ---- A row pointers (shift-gathered), 2 row-sets per wave.
  const unsigned short* arow[2];
#pragma unroll
  for (int s = 0; s < 2; ++s) {
    const int trow = tm * 128 + wave * 32 + s * 16 + l16;
    int bwi = trow / 49;
    int pos = trow - bwi * 49;
    int b = bwi >> 6, win = bwi & 63, wy = win >> 3, wx = win & 7;
    int py = pos / 7, px = pos - py * 7;
    int hh = wy * 7 + py + 3; if (hh >= 56) hh -= 56;
    int wc = wx * 7 + px + 3; if (wc >= 56) wc -= 56;
    arow[s] = xb + (size_t)((b * 56 + hh) * 56 + wc) * 384;
  }

  // ---- B staging base (pre-swizzled source column group).
  const int sw = ((lane & 7) ^ (lane >> 3)) * 8;
  const unsigned short* bq = w + (size_t)(wave * 32 + (lane >> 3)) * 384 + sw;

  const floatx4 zz = {0.f, 0.f, 0.f, 0.f};

  // af[kk] generation kk; loaded one step ahead inside the unrolled loop.
  bf16x8 af[6][2][2];
#pragma unroll
  for (int s = 0; s < 2; ++s)
#pragma unroll
    for (int kh = 0; kh < 2; ++kh)
      af[0][s][kh] = *(const bf16x8*)(arow[s] + (kh * 4 + quad) * 8);

  QSTAGE(tg * 3, 0, 0);

#pragma unroll
  for (int t = 0; t < 3; ++t) {
    const int tn = tg * 3 + t;
    floatx4 acc[2][8];
#pragma unroll
    for (int s = 0; s < 2; ++s)
#pragma unroll
      for (int j = 0; j < 8; ++j) acc[s][j] = zz;

#pragma unroll
    for (int kk = 0; kk < 6; ++kk) {
      const int cur = kk & 1;
      const int kn = (kk < 5) ? kk + 1 : 0;
      // stream next A fragments (next t reuses kk=0: A independent of tn)
#pragma unroll
      for (int s = 0; s < 2; ++s)
#pragma unroll
        for (int kh = 0; kh < 2; ++kh)
          af[kn][s][kh] = *(const bf16x8*)(arow[s] + (kn * 8 + kh * 4 + quad) * 8);
      if (kk < 5) {
        QSTAGE(tn, kk + 1, cur ^ 1);
      } else if (t < 2) {
        QSTAGE(tn + 1, 0, cur ^ 1);
      }
      if (t == 2 && kk == 5) {
        asm volatile("s_waitcnt vmcnt(0)" ::: "memory");
      } else {
        asm volatile("s_waitcnt vmcnt(8)" ::: "memory");
      }
      __builtin_amdgcn_s_barrier();
#pragma unroll
      for (int kh = 0; kh < 2; ++kh) {
#pragma unroll
        for (int g = 0; g < 2; ++g) {
          bf16x8 bfg[4];
#pragma unroll
          for (int j4 = 0; j4 < 4; ++j4) {
            int rb = (g * 4 + j4) * 16 + l16;
            bfg[j4] = *(const bf16x8*)&Bs[cur][rb * 64 + ((((kh << 2) + quad) ^ (rb & 7)) << 3)];
          }
#pragma unroll
          for (int s = 0; s < 2; ++s)
#pragma unroll
            for (int j4 = 0; j4 < 4; ++j4)
              acc[s][g * 4 + j4] = __builtin_amdgcn_mfma_f32_16x16x32_bf16(
                  af[kk][s][kh], bfg[j4], acc[s][g * 4 + j4], 0, 0, 0);
        }
      }
      __builtin_amdgcn_s_barrier();
    }

    // epilogue for this tn: bias + dtype split + store
    float bb[8];
#pragma unroll
    for (int j = 0; j < 8; ++j) bb[j] = bias[tn * 128 + j * 16 + l16];
#pragma unroll
    for (int s = 0; s < 2; ++s) {
#pragma unroll
      for (int r = 0; r < 4; ++r) {
        int t2 = tm * 128 + wave * 32 + s * 16 + quad * 4 + r;
#pragma unroll
        for (int j = 0; j < 8; ++j) {
          int o = tn * 128 + j * 16 + l16;
          float val = acc[s][j][r] + bb[j];
          if (o < 384) {
            qk[(size_t)t2 * 768 + o] = f2bf(val * 0.17677669529663687f);
          } else if (o < 768) {
            qk[(size_t)t2 * 768 + o] = f2bf(val);
          } else {
            vb[(size_t)t2 * 384 + o - 768] = f2bf(val);
          }
        }
      }
    }
  }
}

// ---------------------------------------------------------------------------
// Kernel 2: barrier-free attention. One wave per (window, head). (unchanged)
// ---------------------------------------------------------------------------
#define WSZ 5832
#define VLB 0
#define PB  1960
#define TBB 5488
__global__ __launch_bounds__(256) void attn(
    const unsigned short* __restrict__ qk,
    const unsigned short* __restrict__ vb,
    const float* __restrict__ table,
    unsigned short* __restrict__ ob) {
  __shared__ unsigned short lds[4 * WSZ];
  const int lane = threadIdx.x & 63;
  const int wave = threadIdx.x >> 6, quad = lane >> 4, l16 = lane & 15;
  const int bwh = blockIdx.x * 4 + wave;
  const int bw = bwh / 12, h = bwh - bw * 12;
  const int win = bw & 63, wy = win >> 3, wx = win & 7;
  unsigned short* my = lds + wave * WSZ;
  float* tbf = (float*)(my + TBB);

  bf16x8 zf;
#pragma unroll
  for (int i = 0; i < 8; ++i) zf[i] = (__bf16)0.0f;
  const floatx4 zz = {0.f, 0.f, 0.f, 0.f};

  for (int i = lane; i < 169; i += 64) tbf[i] = table[i * 12 + h];

  const unsigned short* vbase = vb + (size_t)(bw * 49) * 384 + h * 32;
#pragma unroll
  for (int it = 0; it < 4; ++it) {
    int idx = it * 64 + lane;
    int row = idx >> 2, ch = idx & 3;
    if (idx < 196)
      *(bf16x8*)&my[VLB + row * 40 + ch * 8] =
          *(const bf16x8*)(vbase + (size_t)row * 384 + ch * 8);
    else
      *(bf16x8*)&my[VLB + row * 40 + ch * 8] = zf;
  }

  const unsigned short* qbase = qk + (size_t)(bw * 49) * 768 + h * 32;
  bf16x8 aq[4], bk[4];
#pragma unroll
  for (int mt = 0; mt < 4; ++mt) {
    int m = mt * 16 + l16;
    aq[mt] = (m < 49) ? *(const bf16x8*)(qbase + (size_t)m * 768 + quad * 8) : zf;
    bk[mt] = (m < 49) ? *(const bf16x8*)(qbase + 384 + (size_t)m * 768 + quad * 8) : zf;
  }

  floatx4 s[4][4];
#pragma unroll
  for (int mt = 0; mt < 4; ++mt)
#pragma unroll
    for (int nt = 0; nt < 4; ++nt)
      s[mt][nt] = __builtin_amdgcn_mfma_f32_16x16x32_bf16(aq[mt], bk[nt], zz, 0, 0, 0);

  int yj[4], xj[4], ccv[4];
#pragma unroll
  for (int nt = 0; nt < 4; ++nt) {
    int j = nt * 16 + l16;
    int y = (j * 37) >> 8, xx = j - y * 7;
    yj[nt] = y; xj[nt] = xx;
    ccv[nt] = reg3(wy * 7 + y) * 3 + reg3(wx * 7 + xx);
  }

  const float NEG = -1e30f;
#pragma unroll
  for (int mt = 0; mt < 4; ++mt) {
#pragma unroll
    for (int r = 0; r < 4; ++r) {
      int i = mt * 16 + quad * 4 + r;
      int yi = (i * 37) >> 8, xi = i - yi * 7;
      int rc = reg3(wy * 7 + yi) * 3 + reg3(wx * 7 + xi);
      bool rowok = (i < 49);
      float vals[4];
      float mx = NEG;
#pragma unroll
      for (int nt = 0; nt < 4; ++nt) {
        int j = nt * 16 + l16;
        float v = s[mt][nt][r];
        if (rowok && j < 49) {
          v += tbf[(yi - yj[nt] + 6) * 13 + (xi - xj[nt] + 6)];
          if (rc != ccv[nt]) v -= 100.0f;
        } else {
          v = NEG;
        }
        vals[nt] = v;
        mx = fmaxf(mx, v);
      }
#pragma unroll
      for (int off = 1; off < 16; off <<= 1)
        mx = fmaxf(mx, __shfl_xor(mx, off, 64));
      float sum = 0.f;
#pragma unroll
      for (int nt = 0; nt < 4; ++nt) {
        float e = __expf(vals[nt] - mx);
        vals[nt] = e;
        sum += e;
      }
#pragma unroll
      for (int off = 1; off < 16; off <<= 1) sum += __shfl_xor(sum, off, 64);
      float rinv = 1.f / sum;
      if (rowok) {
#pragma unroll
        for (int nt = 0; nt < 4; ++nt)
          my[PB + i * 72 + nt * 16 + l16] = f2bf(vals[nt] * rinv);
      }
    }
  }

  floatx4 oacc[4][2];
#pragma unroll
  for (int mt = 0; mt < 4; ++mt) { oacc[mt][0] = zz; oacc[mt][1] = zz; }
#pragma unroll
  for (int ks2 = 0; ks2 < 2; ++ks2) {
    bf16x8 bv[2];
#pragma unroll
    for (int nt = 0; nt < 2; ++nt) {
#pragma unroll
      for (int jj = 0; jj < 8; ++jj)
        bv[nt][jj] = __builtin_bit_cast(
            __bf16, my[VLB + (ks2 * 32 + quad * 8 + jj) * 40 + nt * 16 + l16]);
    }
#pragma unroll
    for (int mt = 0; mt < 4; ++mt) {
      int m = mt * 16 + l16;
      bf16x8 ap = (m < 49)
          ? *(const bf16x8*)&my[PB + m * 72 + ks2 * 32 + quad * 8] : zf;
#pragma unroll
      for (int nt = 0; nt < 2; ++nt)
        oacc[mt][nt] = __builtin_amdgcn_mfma_f32_16x16x32_bf16(ap, bv[nt], oacc[mt][nt], 0, 0, 0);
    }
  }

  unsigned short* obase = ob + (size_t)(bw * 49) * 384 + h * 32;
#pragma unroll
  for (int mt = 0; mt < 4; ++mt) {
#pragma unroll
    for (int r = 0; r < 4; ++r) {
      int i = mt * 16 + quad * 4 + r;
      if (i < 49) {
#pragma unroll
        for (int nt = 0; nt < 2; ++nt)
          obase[(size_t)i * 384 + nt * 16 + l16] = f2bf(oacc[mt][nt][r]);
      }
    }
  }
}

// ---------------------------------------------------------------------------
// Kernel 3: proj GEMM, A-stationary, 2 A-frags/wave, streamed af, single tn
// per block (grid 392x3). fp32 out + inverse-shift scatter + bias.
// ---------------------------------------------------------------------------
__global__ __launch_bounds__(256, 3) void proj_gemm(
    const unsigned short* __restrict__ a,
    const unsigned short* __restrict__ w,
    const float* __restrict__ bias,
    float* __restrict__ out) {
  __shared__ unsigned short Bs[2][128 * 64];
  const int tid = threadIdx.x;
  const int wave = tid >> 6, lane = tid & 63, quad = lane >> 4, l16 = lane & 15;
  const int tm = blockIdx.x;  // 0..391 (128 rows each)
  const int tn = blockIdx.y;  // 0..2

  const unsigned short* arow[2];
#pragma unroll
  for (int s = 0; s < 2; ++s) {
    const int trow = tm * 128 + wave * 32 + s * 16 + l16;
    arow[s] = a + (size_t)trow * 384;
  }

  const int sw = ((lane & 7) ^ (lane >> 3)) * 8;
  const unsigned short* bq = w + (size_t)(wave * 32 + (lane >> 3)) * 384 + sw;

  const floatx4 zz = {0.f, 0.f, 0.f, 0.f};

  bf16x8 af[6][2][2];
#pragma unroll
  for (int s = 0; s < 2; ++s)
#pragma unroll
    for (int kh = 0; kh < 2; ++kh)
      af[0][s][kh] = *(const bf16x8*)(arow[s] + (kh * 4 + quad) * 8);

  floatx4 acc[2][8];
#pragma unroll
  for (int s = 0; s < 2; ++s)
#pragma unroll
    for (int j = 0; j < 8; ++j) acc[s][j] = zz;

  QSTAGE(tn, 0, 0);

#pragma unroll
  for (int kk = 0; kk < 6; ++kk) {
    const int cur = kk & 1;
    const int kn = (kk < 5) ? kk + 1 : 0;
#pragma unroll
    for (int s = 0; s < 2; ++s)
#pragma unroll
      for (int kh = 0; kh < 2; ++kh)
        af[kn][s][kh] = *(const bf16x8*)(arow[s] + (kn * 8 + kh * 4 + quad) * 8);
    if (kk < 5) {
      QSTAGE(tn, kk + 1, cur ^ 1);
      asm volatile("s_waitcnt vmcnt(8)" ::: "memory");
    } else {
      asm volatile("s_waitcnt vmcnt(0)" ::: "memory");
    }
    __builtin_amdgcn_s_barrier();
#pragma unroll
    for (int kh = 0; kh < 2; ++kh) {
#pragma unroll
      for (int g = 0; g < 2; ++g) {
        bf16x8 bfg[4];
#pragma unroll
        for (int j4 = 0; j4 < 4; ++j4) {
          int rb = (g * 4 + j4) * 16 + l16;
          bfg[j4] = *(const bf16x8*)&Bs[cur][rb * 64 + ((((kh << 2) + quad) ^ (rb & 7)) << 3)];
        }
#pragma unroll
        for (int s = 0; s < 2; ++s)
#pragma unroll
          for (int j4 = 0; j4 < 4; ++j4)
            acc[s][g * 4 + j4] = __builtin_amdgcn_mfma_f32_16x16x32_bf16(
                af[kk][s][kh], bfg[j4], acc[s][g * 4 + j4], 0, 0, 0);
      }
    }
    __builtin_amdgcn_s_barrier();
  }

  // epilogue: compute inverse-shift scatter bases here (keeps live range short)
  float bb[8];
#pragma unroll
  for (int j = 0; j < 8; ++j) bb[j] = bias[tn * 128 + j * 16 + l16];
#pragma unroll
  for (int s = 0; s < 2; ++s) {
#pragma unroll
    for (int r = 0; r < 4; ++r) {
      int t2 = tm * 128 + wave * 32 + s * 16 + quad * 4 + r;
      int bwi = t2 / 49;
      int pos = t2 - bwi * 49;
      int b = bwi >> 6, win = bwi & 63, wy = win >> 3, wx = win & 7;
      int py = pos / 7, px = pos - py * 7;
      int hh = wy * 7 + py + 3; if (hh >= 56) hh -= 56;
      int wc = wx * 7 + px + 3; if (wc >= 56) wc -= 56;
      size_t base = (size_t)((b * 56 + hh) * 56 + wc) * 384;
#pragma unroll
      for (int j = 0; j < 8; ++j) {
        int o = tn * 128 + j * 16 + l16;
        out[base + o] = acc[s][j][r] + bb[j];
      }
    }
  }
}

// ===========================================================================
// Fallback path (round-4, passing at 858 us) for small workspace.
// ===========================================================================
#define XW 0
#define QO 19208
#define KO 21768
#define VT 24328
#define PO 19208
#define LDSN 26632

__global__ __launch_bounds__(256) void swin_fused(
    const float* __restrict__ x, const float* __restrict__ w,
    const float* __restrict__ qkvb, const float* __restrict__ table,
    float* __restrict__ out) {
  __shared__ unsigned short lds[LDSN];
  const int tid = threadIdx.x;
  const int wave = tid >> 6, lane = tid & 63, quad = lane >> 4, l16 = lane & 15;
  const int bw = blockIdx.x;
  const int b = bw >> 6, win = bw & 63, wy = win >> 3, wx = win & 7;

  bf16x8 zf;
#pragma unroll
  for (int i = 0; i < 8; ++i) zf[i] = (__bf16)0.0f;
  const floatx4 zz = {0.f, 0.f, 0.f, 0.f};

  for (int c = tid; c < 2352; c += 256) {
    int r = c / 48, c8 = c - r * 48;
    int py = (r * 37) >> 8, px = r - py * 7;
    int hh = wy * 7 + py + 3; if (hh >= 56) hh -= 56;
    int wc = wx * 7 + px + 3; if (wc >= 56) wc -= 56;
    *(bf16x8*)&lds[XW + r * 392 + c8 * 8] =
        cvt8(x + (size_t)((b * 56 + hh) * 56 + wc) * 384 + c8 * 8);
  }
  __syncthreads();

  int yj[4], xj[4], ccv[4];
#pragma unroll
  for (int nt = 0; nt < 4; ++nt) {
    int j = nt * 16 + l16;
    int y = (j * 37) >> 8, xx = j - y * 7;
    yj[nt] = y; xj[nt] = xx;
    ccv[nt] = reg3(wy * 7 + y) * 3 + reg3(wx * 7 + xx);
  }

  for (int g = 0; g < 3; ++g) {
    const int hme = g * 4 + wave;
    const float* bp[6];
    int wrowv[6];
#pragma unroll
    for (int nt = 0; nt < 6; ++nt) {
      int which = nt >> 1;
      int n32 = (nt & 1) * 16 + l16;
      int wrow = which * 384 + hme * 32 + n32;
      wrowv[nt] = wrow;
      bp[nt] = w + (size_t)wrow * 384 + quad * 8;
    }

    floatx4 acc[4][6];
#pragma unroll
    for (int mt = 0; mt < 4; ++mt)
#pragma unroll
      for (int nt = 0; nt < 6; ++nt) acc[mt][nt] = zz;

    for (int ks = 0; ks < 12; ++ks) {
      bf16x8 af[4];
#pragma unroll
      for (int mt = 0; mt < 4; ++mt) {
        int am = mt * 16 + l16;
        af[mt] = (am < 49) ? *(const bf16x8*)&lds[XW + am * 392 + ks * 32 + quad * 8] : zf;
      }
#pragma unroll
      for (int nt = 0; nt < 6; ++nt) {
        bf16x8 bfr = cvt8(bp[nt] + ks * 32);
#pragma unroll
        for (int mt = 0; mt < 4; ++mt)
          acc[mt][nt] = __builtin_amdgcn_mfma_f32_16x16x32_bf16(af[mt], bfr, acc[mt][nt], 0, 0, 0);
      }
    }

    for (int hh2 = 0; hh2 < 4; ++hh2) {
      const int h = g * 4 + hh2;
      __syncthreads();
      if (wave == hh2) {
        float bb[6];
#pragma unroll
        for (int nt = 0; nt < 6; ++nt) bb[nt] = qkvb[wrowv[nt]];
#pragma unroll
        for (int mt = 0; mt < 4; ++mt) {
#pragma unroll
          for (int r = 0; r < 4; ++r) {
            int token = mt * 16 + quad * 4 + r;
#pragma unroll
            for (int nt = 0; nt < 6; ++nt) {
              float val = acc[mt][nt][r] + bb[nt];
              int n32 = (nt & 1) * 16 + l16;
              if (nt < 2)
                lds[QO + token * 40 + n32] = f2bf(val * 0.17677669529663687f);
              else if (nt < 4)
                lds[KO + token * 40 + n32] = f2bf(val);
              else
                lds[VT + n32 * 72 + token] = f2bf(val);
            }
          }
        }
      }
      __syncthreads();

      bf16x8 aq = *(const bf16x8*)&lds[QO + (wave * 16 + l16) * 40 + quad * 8];
      bf16x8 bk[4];
#pragma unroll
      for (int nt = 0; nt < 4; ++nt)
        bk[nt] = *(const bf16x8*)&lds[KO + (nt * 16 + l16) * 40 + quad * 8];
      bf16x8 bv[2][2];
#pragma unroll
      for (int nt = 0; nt < 2; ++nt)
#pragma unroll
        for (int ks = 0; ks < 2; ++ks)
          bv[nt][ks] = *(const bf16x8*)&lds[VT + (nt * 16 + l16) * 72 + ks * 32 + quad * 8];
      __syncthreads();

      floatx4 s4[4];
#pragma unroll
      for (int nt = 0; nt < 4; ++nt)
        s4[nt] = __builtin_amdgcn_mfma_f32_16x16x32_bf16(aq, bk[nt], zz, 0, 0, 0);

      const float NEG = -1e30f;
#pragma unroll
      for (int r = 0; r < 4; ++r) {
        int i = wave * 16 + quad * 4 + r;
        int yi = (i * 37) >> 8, xi = i - yi * 7;
        int rc = reg3(wy * 7 + yi) * 3 + reg3(wx * 7 + xi);
        bool rowok = (i < 49);
        float vals[4];
        float mx = NEG;
#pragma unroll
        for (int nt = 0; nt < 4; ++nt) {
          int j = nt * 16 + l16;
          float v = s4[nt][r];
          if (rowok && j < 49) {
            v += table[((yi - yj[nt] + 6) * 13 + (xi - xj[nt] + 6)) * 12 + h];
            if (rc != ccv[nt]) v -= 100.0f;
          } else {
            v = NEG;
          }
          vals[nt] = v;
          mx = fmaxf(mx, v);
        }
#pragma unroll
        for (int off = 1; off < 16; off <<= 1)
          mx = fmaxf(mx, __shfl_xor(mx, off, 64));
        float sum = 0.f;
#pragma unroll
        for (int nt = 0; nt < 4; ++nt) {
          float e = __expf(vals[nt] - mx);
          vals[nt] = e;
          sum += e;
        }
#pragma unroll
        for (int off = 1; off < 16; off <<= 1) sum += __shfl_xor(sum, off, 64);
        float rinv = 1.f / sum;
#pragma unroll
        for (int nt = 0; nt < 4; ++nt)
          lds[PO + i * 72 + nt * 16 + l16] = f2bf(vals[nt] * rinv);
      }
      __syncthreads();

      bf16x8 ap[2];
#pragma unroll
      for (int ks = 0; ks < 2; ++ks)
        ap[ks] = *(const bf16x8*)&lds[PO + (wave * 16 + l16) * 72 + ks * 32 + quad * 8];
      floatx4 o2[2] = {zz, zz};
#pragma unroll
      for (int ks = 0; ks < 2; ++ks)
#pragma unroll
        for (int nt = 0; nt < 2; ++nt)
          o2[nt] = __builtin_amdgcn_mfma_f32_16x16x32_bf16(ap[ks], bv[nt][ks], o2[nt], 0, 0, 0);

#pragma unroll
      for (int r = 0; r < 4; ++r) {
        int i = wave * 16 + quad * 4 + r;
        if (i < 49) {
          int py = (i * 37) >> 8, px = i - py * 7;
          int hh = wy * 7 + py + 3; if (hh >= 56) hh -= 56;
          int wc = wx * 7 + px + 3; if (wc >= 56) wc -= 56;
          size_t base = (size_t)((b * 56 + hh) * 56 + wc) * 384 + h * 32;
#pragma unroll
          for (int nt = 0; nt < 2; ++nt)
            out[base + nt * 16 + l16] = o2[nt][r];
        }
      }
    }
  }
}

__global__ __launch_bounds__(256) void proj_inplace(
    float* __restrict__ out, const float* __restrict__ w,
    const float* __restrict__ pb) {
  __shared__ unsigned short A[64 * 392];
  const int tid = threadIdx.x;
  const int wave = tid >> 6, lane = tid & 63, quad = lane >> 4, l16 = lane & 15;
  const int tm = blockIdx.x;

  for (int c = tid; c < 3072; c += 256) {
    int r = c / 48, c8 = c - r * 48;
    *(bf16x8*)&A[r * 392 + c8 * 8] = cvt8(out + (size_t)(tm * 64 + r) * 384 + c8 * 8);
  }
  __syncthreads();

  const float* bp[6];
#pragma unroll
  for (int nt = 0; nt < 6; ++nt)
    bp[nt] = w + (size_t)(wave * 96 + nt * 16 + l16) * 384 + quad * 8;

  const floatx4 zz = {0.f, 0.f, 0.f, 0.f};
  floatx4 acc[4][6];
#pragma unroll
  for (int mt = 0; mt < 4; ++mt)
#pragma unroll
    for (int nt = 0; nt < 6; ++nt) acc[mt][nt] = zz;

  for (int ks = 0; ks < 12; ++ks) {
    bf16x8 af[4];
#pragma unroll
    for (int mt = 0; mt < 4; ++mt)
      af[mt] = *(const bf16x8*)&A[(mt * 16 + l16) * 392 + ks * 32 + quad * 8];
#pragma unroll
    for (int nt = 0; nt < 6; ++nt) {
      bf16x8 bfr = cvt8(bp[nt] + ks * 32);
#pragma unroll
      for (int mt = 0; mt < 4; ++mt)
        acc[mt][nt] = __builtin_amdgcn_mfma_f32_16x16x32_bf16(af[mt], bfr, acc[mt][nt], 0, 0, 0);
    }
  }

#pragma unroll
  for (int mt = 0; mt < 4; ++mt) {
#pragma unroll
    for (int r = 0; r < 4; ++r) {
      int t = tm * 64 + mt * 16 + quad * 4 + r;
#pragma unroll
      for (int nt = 0; nt < 6; ++nt) {
        int col = wave * 96 + nt * 16 + l16;
        out[(size_t)t * 384 + col] = acc[mt][nt][r] + pb[col];
      }
    }
  }
}

extern "C" void kernel_launch(void* const* d_in, const int* in_sizes, int n_in,
                              void* d_out, int out_size, void* d_ws, size_t ws_size,
                              hipStream_t stream) {
  const float* x      = (const float*)d_in[0];
  const float* qkv_w  = (const float*)d_in[1];
  const float* qkv_b  = (const float*)d_in[2];
  const float* proj_w = (const float*)d_in[3];
  const float* proj_b = (const float*)d_in[4];
  const float* table  = (const float*)d_in[5];
  float* out = (float*)d_out;

  const size_t NEED = (size_t)(NX + NQW + NPW + NX + NX) * 2;  // 116,785,152 B
  if (ws_size >= NEED) {
    unsigned short* xb  = (unsigned short*)d_ws;
    unsigned short* wqb = xb + NX;
    unsigned short* wpb = wqb + NQW;
    unsigned short* vb  = wpb + NPW;
    unsigned short* ob  = vb + NX;
    unsigned short* qkb = (unsigned short*)d_out;  // q+k scratch fills d_out exactly

    cvt_all<<<9696, 256, 0, stream>>>(x, qkv_w, proj_w, xb, wqb, wpb);
    dim3 g1(392, 3);
    qkv_gemm<<<g1, 256, 0, stream>>>(xb, wqb, qkv_b, qkb, vb);
    attn<<<3072, 256, 0, stream>>>(qkb, vb, table, ob);
    dim3 g3(392, 3);
    proj_gemm<<<g3, 256, 0, stream>>>(ob, wpb, proj_b, out);
  } else {
    swin_fused<<<1024, 256, 0, stream>>>(x, qkv_w, qkv_b, table, out);
    proj_inplace<<<784, 256, 0, stream>>>(out, proj_w, proj_b);
  }
}

// Round 8
// 286.875 us; speedup vs baseline: 1.0717x; 1.0717x over previous
//
#include <hip/hip_runtime.h>
#include <hip/hip_bf16.h>
#include <stdint.h>

typedef __attribute__((ext_vector_type(8))) __bf16 bf16x8;
typedef __attribute__((ext_vector_type(4))) float floatx4;

__device__ __forceinline__ unsigned short f2bf(float f) {
  __hip_bfloat16 h = __float2bfloat16(f);
  return __builtin_bit_cast(unsigned short, h);
}
__device__ __forceinline__ __bf16 f2b(float f) {
  return __builtin_bit_cast(__bf16, f2bf(f));
}
__device__ __forceinline__ float bf2f(unsigned short u) {
  __hip_bfloat16 h = __builtin_bit_cast(__hip_bfloat16, u);
  return __bfloat162float(h);
}
__device__ __forceinline__ bf16x8 cvt8(const float* p) {
  floatx4 a = *(const floatx4*)p;
  floatx4 b = *(const floatx4*)(p + 4);
  bf16x8 r;
#pragma unroll
  for (int i = 0; i < 4; ++i) { r[i] = f2b(a[i]); r[4 + i] = f2b(b[i]); }
  return r;
}
__device__ __forceinline__ void gload_lds16(const unsigned short* g, unsigned short* l) {
  __builtin_amdgcn_global_load_lds(
      (const __attribute__((address_space(1))) unsigned int*)g,
      (__attribute__((address_space(3))) unsigned int*)l, 16, 0, 0);
}
__device__ __forceinline__ int reg3(int t) { return t < 49 ? 0 : (t < 53 ? 1 : 2); }

#define NX 19267584
#define NQW 442368
#define NPW 147456

// ---------------------------------------------------------------------------
// Kernel 0: fp32 -> bf16 conversion of qkv_w, proj_w only (x is converted
// in-register inside qkv_gemm). 288 blocks exactly covers NQW+NPW.
// ---------------------------------------------------------------------------
__global__ __launch_bounds__(256) void cvt_w(
    const float* __restrict__ wq, const float* __restrict__ wp,
    unsigned short* __restrict__ wqb, unsigned short* __restrict__ wpb) {
  int i = (blockIdx.x * 256 + threadIdx.x) * 8;
  if (i < NQW) {
    *(bf16x8*)(wqb + i) = cvt8(wq + i);
  } else {
    int o = i - NQW;
    *(bf16x8*)(wpb + o) = cvt8(wp + o);
  }
}

// ---------------------------------------------------------------------------
// Kernel 1: fused shift-gather + fp32->bf16 + QKV GEMM, A-stationary (R2
// structure: one A row per lane in registers, loaded ONCE per block, all 9
// tn tiles chained). B double-buffered in LDS, XOR swizzle, counted vmcnt(4).
// ---------------------------------------------------------------------------
#define QSTAGE(TN, KK, BUF)                                                   \
  {                                                                           \
    _Pragma("unroll") for (int s = 0; s < 4; ++s)                             \
        gload_lds16(bq + ((size_t)(TN) * 128 + s * 8) * 384 + (KK) * 64,      \
                    &Bs[BUF][(wave * 32 + s * 8) * 64]);                      \
  }

__global__ __launch_bounds__(256, 3) void qkv_gemm(
    const float* __restrict__ x,
    const unsigned short* __restrict__ w,
    const float* __restrict__ bias,
    unsigned short* __restrict__ qk,
    unsigned short* __restrict__ vb) {
  __shared__ unsigned short Bs[2][128 * 64];
  const int tid = threadIdx.x;
  const int wave = tid >> 6, lane = tid & 63, quad = lane >> 4, l16 = lane & 15;
  const int tm = blockIdx.x;  // 0..783

  // ---- A: one shift-gathered fp32 row per lane, converted to 12x bf16x8.
  const int trow = tm * 64 + wave * 16 + l16;
  int bwi = trow / 49;
  int pos = trow - bwi * 49;
  int b = bwi >> 6, win = bwi & 63, wy = win >> 3, wx = win & 7;
  int py = pos / 7, px = pos - py * 7;
  int hh = wy * 7 + py + 3; if (hh >= 56) hh -= 56;
  int wc = wx * 7 + px + 3; if (wc >= 56) wc -= 56;
  const float* arow = x + (size_t)((b * 56 + hh) * 56 + wc) * 384;

  bf16x8 af[6][2];
#pragma unroll
  for (int kk = 0; kk < 6; ++kk)
#pragma unroll
    for (int kh = 0; kh < 2; ++kh)
      af[kk][kh] = cvt8(arow + (kk * 8 + kh * 4 + quad) * 8);

  // ---- B staging base (pre-swizzled source column group).
  const int sw = ((lane & 7) ^ (lane >> 3)) * 8;
  const unsigned short* bq = w + (size_t)(wave * 32 + (lane >> 3)) * 384 + sw;

  const floatx4 zz = {0.f, 0.f, 0.f, 0.f};
  const int orow = tm * 64 + wave * 16 + quad * 4;  // +r at store time

  QSTAGE(0, 0, 0);

  for (int tn = 0; tn < 9; ++tn) {
    floatx4 acc[8];
#pragma unroll
    for (int j = 0; j < 8; ++j) acc[j] = zz;

#pragma unroll
    for (int kk = 0; kk < 6; ++kk) {
      const int cur = kk & 1;
      if (kk < 5) {
        QSTAGE(tn, kk + 1, cur ^ 1);
        asm volatile("s_waitcnt vmcnt(4)" ::: "memory");
      } else if (tn < 8) {
        QSTAGE(tn + 1, 0, cur ^ 1);
        asm volatile("s_waitcnt vmcnt(4)" ::: "memory");
      } else {
        asm volatile("s_waitcnt vmcnt(0)" ::: "memory");
      }
      __builtin_amdgcn_s_barrier();
#pragma unroll
      for (int kh = 0; kh < 2; ++kh) {
        bf16x8 bfg[8];
#pragma unroll
        for (int j = 0; j < 8; ++j) {
          int rb = j * 16 + l16;
          bfg[j] = *(const bf16x8*)&Bs[cur][rb * 64 + ((((kh << 2) + quad) ^ (rb & 7)) << 3)];
        }
#pragma unroll
        for (int j = 0; j < 8; ++j)
          acc[j] = __builtin_amdgcn_mfma_f32_16x16x32_bf16(af[kk][kh], bfg[j], acc[j], 0, 0, 0);
      }
      __builtin_amdgcn_s_barrier();
    }

    // epilogue for this tn: bias + dtype split + store
    float bb[8];
#pragma unroll
    for (int j = 0; j < 8; ++j) bb[j] = bias[tn * 128 + j * 16 + l16];
#pragma unroll
    for (int r = 0; r < 4; ++r) {
      int t = orow + r;
#pragma unroll
      for (int j = 0; j < 8; ++j) {
        int o = tn * 128 + j * 16 + l16;
        float val = acc[j][r] + bb[j];
        if (o < 384) {
          qk[(size_t)t * 768 + o] = f2bf(val * 0.17677669529663687f);
        } else if (o < 768) {
          qk[(size_t)t * 768 + o] = f2bf(val);
        } else {
          vb[(size_t)t * 384 + o - 768] = f2bf(val);
        }
      }
    }
  }
}

// ---------------------------------------------------------------------------
// Kernel 2: barrier-free attention. One wave per (window, head).
// R2-VERBATIM (vL stride 40 + scalar V gather) — known-good.
// ---------------------------------------------------------------------------
#define WSZ 5832
#define VLB 0
#define PB  1960
#define TBB 5488
__global__ __launch_bounds__(256) void attn(
    const unsigned short* __restrict__ qk,
    const unsigned short* __restrict__ vb,
    const float* __restrict__ table,
    unsigned short* __restrict__ ob) {
  __shared__ unsigned short lds[4 * WSZ];
  const int lane = threadIdx.x & 63;
  const int wave = threadIdx.x >> 6, quad = lane >> 4, l16 = lane & 15;
  const int bwh = blockIdx.x * 4 + wave;
  const int bw = bwh / 12, h = bwh - bw * 12;
  const int win = bw & 63, wy = win >> 3, wx = win & 7;
  unsigned short* my = lds + wave * WSZ;
  float* tbf = (float*)(my + TBB);

  bf16x8 zf;
#pragma unroll
  for (int i = 0; i < 8; ++i) zf[i] = (__bf16)0.0f;
  const floatx4 zz = {0.f, 0.f, 0.f, 0.f};

  for (int i = lane; i < 169; i += 64) tbf[i] = table[i * 12 + h];

  const unsigned short* vbase = vb + (size_t)(bw * 49) * 384 + h * 32;
#pragma unroll
  for (int it = 0; it < 4; ++it) {
    int idx = it * 64 + lane;
    int row = idx >> 2, ch = idx & 3;
    if (idx < 196)
      *(bf16x8*)&my[VLB + row * 40 + ch * 8] =
          *(const bf16x8*)(vbase + (size_t)row * 384 + ch * 8);
    else
      *(bf16x8*)&my[VLB + row * 40 + ch * 8] = zf;
  }

  const unsigned short* qbase = qk + (size_t)(bw * 49) * 768 + h * 32;
  bf16x8 aq[4], bk[4];
#pragma unroll
  for (int mt = 0; mt < 4; ++mt) {
    int m = mt * 16 + l16;
    aq[mt] = (m < 49) ? *(const bf16x8*)(qbase + (size_t)m * 768 + quad * 8) : zf;
    bk[mt] = (m < 49) ? *(const bf16x8*)(qbase + 384 + (size_t)m * 768 + quad * 8) : zf;
  }

  floatx4 s[4][4];
#pragma unroll
  for (int mt = 0; mt < 4; ++mt)
#pragma unroll
    for (int nt = 0; nt < 4; ++nt)
      s[mt][nt] = __builtin_amdgcn_mfma_f32_16x16x32_bf16(aq[mt], bk[nt], zz, 0, 0, 0);

  int yj[4], xj[4], ccv[4];
#pragma unroll
  for (int nt = 0; nt < 4; ++nt) {
    int j = nt * 16 + l16;
    int y = (j * 37) >> 8, xx = j - y * 7;
    yj[nt] = y; xj[nt] = xx;
    ccv[nt] = reg3(wy * 7 + y) * 3 + reg3(wx * 7 + xx);
  }

  const float NEG = -1e30f;
#pragma unroll
  for (int mt = 0; mt < 4; ++mt) {
#pragma unroll
    for (int r = 0; r < 4; ++r) {
      int i = mt * 16 + quad * 4 + r;
      int yi = (i * 37) >> 8, xi = i - yi * 7;
      int rc = reg3(wy * 7 + yi) * 3 + reg3(wx * 7 + xi);
      bool rowok = (i < 49);
      float vals[4];
      float mx = NEG;
#pragma unroll
      for (int nt = 0; nt < 4; ++nt) {
        int j = nt * 16 + l16;
        float v = s[mt][nt][r];
        if (rowok && j < 49) {
          v += tbf[(yi - yj[nt] + 6) * 13 + (xi - xj[nt] + 6)];
          if (rc != ccv[nt]) v -= 100.0f;
        } else {
          v = NEG;
        }
        vals[nt] = v;
        mx = fmaxf(mx, v);
      }
#pragma unroll
      for (int off = 1; off < 16; off <<= 1)
        mx = fmaxf(mx, __shfl_xor(mx, off, 64));
      float sum = 0.f;
#pragma unroll
      for (int nt = 0; nt < 4; ++nt) {
        float e = __expf(vals[nt] - mx);
        vals[nt] = e;
        sum += e;
      }
#pragma unroll
      for (int off = 1; off < 16; off <<= 1) sum += __shfl_xor(sum, off, 64);
      float rinv = 1.f / sum;
      if (rowok) {
#pragma unroll
        for (int nt = 0; nt < 4; ++nt)
          my[PB + i * 72 + nt * 16 + l16] = f2bf(vals[nt] * rinv);
      }
    }
  }

  floatx4 oacc[4][2];
#pragma unroll
  for (int mt = 0; mt < 4; ++mt) { oacc[mt][0] = zz; oacc[mt][1] = zz; }
#pragma unroll
  for (int ks2 = 0; ks2 < 2; ++ks2) {
    bf16x8 bv[2];
#pragma unroll
    for (int nt = 0; nt < 2; ++nt) {
#pragma unroll
      for (int jj = 0; jj < 8; ++jj)
        bv[nt][jj] = __builtin_bit_cast(
            __bf16, my[VLB + (ks2 * 32 + quad * 8 + jj) * 40 + nt * 16 + l16]);
    }
#pragma unroll
    for (int mt = 0; mt < 4; ++mt) {
      int m = mt * 16 + l16;
      bf16x8 ap = (m < 49)
          ? *(const bf16x8*)&my[PB + m * 72 + ks2 * 32 + quad * 8] : zf;
#pragma unroll
      for (int nt = 0; nt < 2; ++nt)
        oacc[mt][nt] = __builtin_amdgcn_mfma_f32_16x16x32_bf16(ap, bv[nt], oacc[mt][nt], 0, 0, 0);
    }
  }

  unsigned short* obase = ob + (size_t)(bw * 49) * 384 + h * 32;
#pragma unroll
  for (int mt = 0; mt < 4; ++mt) {
#pragma unroll
    for (int r = 0; r < 4; ++r) {
      int i = mt * 16 + quad * 4 + r;
      if (i < 49) {
#pragma unroll
        for (int nt = 0; nt < 2; ++nt)
          obase[(size_t)i * 384 + nt * 16 + l16] = f2bf(oacc[mt][nt][r]);
      }
    }
  }
}

// ---------------------------------------------------------------------------
// Kernel 3: proj GEMM, A-stationary (R2 structure: 784 blocks, 64 rows, 3 tn
// chained). fp32 out + inverse-shift scatter + bias.
// ---------------------------------------------------------------------------
__global__ __launch_bounds__(256, 3) void proj_gemm(
    const unsigned short* __restrict__ a,
    const unsigned short* __restrict__ w,
    const float* __restrict__ bias,
    float* __restrict__ out) {
  __shared__ unsigned short Bs[2][128 * 64];
  const int tid = threadIdx.x;
  const int wave = tid >> 6, lane = tid & 63, quad = lane >> 4, l16 = lane & 15;
  const int tm = blockIdx.x;  // 0..783

  const int trow = tm * 64 + wave * 16 + l16;
  const unsigned short* arow = a + (size_t)trow * 384;

  bf16x8 af[6][2];
#pragma unroll
  for (int kk = 0; kk < 6; ++kk)
#pragma unroll
    for (int kh = 0; kh < 2; ++kh)
      af[kk][kh] = *(const bf16x8*)(arow + (kk * 8 + kh * 4 + quad) * 8);

  const int sw = ((lane & 7) ^ (lane >> 3)) * 8;
  const unsigned short* bq = w + (size_t)(wave * 32 + (lane >> 3)) * 384 + sw;

  const floatx4 zz = {0.f, 0.f, 0.f, 0.f};

  // precompute inverse-shift scatter bases for this lane's 4 output rows
  size_t obase[4];
#pragma unroll
  for (int r = 0; r < 4; ++r) {
    int t = tm * 64 + wave * 16 + quad * 4 + r;
    int bwi = t / 49;
    int pos = t - bwi * 49;
    int b = bwi >> 6, win = bwi & 63, wy = win >> 3, wx = win & 7;
    int py = pos / 7, px = pos - py * 7;
    int hh = wy * 7 + py + 3; if (hh >= 56) hh -= 56;
    int wc = wx * 7 + px + 3; if (wc >= 56) wc -= 56;
    obase[r] = (size_t)((b * 56 + hh) * 56 + wc) * 384;
  }

  QSTAGE(0, 0, 0);

  for (int tn = 0; tn < 3; ++tn) {
    floatx4 acc[8];
#pragma unroll
    for (int j = 0; j < 8; ++j) acc[j] = zz;

#pragma unroll
    for (int kk = 0; kk < 6; ++kk) {
      const int cur = kk & 1;
      if (kk < 5) {
        QSTAGE(tn, kk + 1, cur ^ 1);
        asm volatile("s_waitcnt vmcnt(4)" ::: "memory");
      } else if (tn < 2) {
        QSTAGE(tn + 1, 0, cur ^ 1);
        asm volatile("s_waitcnt vmcnt(4)" ::: "memory");
      } else {
        asm volatile("s_waitcnt vmcnt(0)" ::: "memory");
      }
      __builtin_amdgcn_s_barrier();
#pragma unroll
      for (int kh = 0; kh < 2; ++kh) {
        bf16x8 bfg[8];
#pragma unroll
        for (int j = 0; j < 8; ++j) {
          int rb = j * 16 + l16;
          bfg[j] = *(const bf16x8*)&Bs[cur][rb * 64 + ((((kh << 2) + quad) ^ (rb & 7)) << 3)];
        }
#pragma unroll
        for (int j = 0; j < 8; ++j)
          acc[j] = __builtin_amdgcn_mfma_f32_16x16x32_bf16(af[kk][kh], bfg[j], acc[j], 0, 0, 0);
      }
      __builtin_amdgcn_s_barrier();
    }

    float bb[8];
#pragma unroll
    for (int j = 0; j < 8; ++j) bb[j] = bias[tn * 128 + j * 16 + l16];
#pragma unroll
    for (int r = 0; r < 4; ++r) {
#pragma unroll
      for (int j = 0; j < 8; ++j) {
        int o = tn * 128 + j * 16 + l16;
        out[obase[r] + o] = acc[j][r] + bb[j];
      }
    }
  }
}

// ===========================================================================
// Fallback path (round-4, passing at 858 us) for small workspace.
// ===========================================================================
#define XW 0
#define QO 19208
#define KO 21768
#define VT 24328
#define PO 19208
#define LDSN 26632

__global__ __launch_bounds__(256) void swin_fused(
    const float* __restrict__ x, const float* __restrict__ w,
    const float* __restrict__ qkvb, const float* __restrict__ table,
    float* __restrict__ out) {
  __shared__ unsigned short lds[LDSN];
  const int tid = threadIdx.x;
  const int wave = tid >> 6, lane = tid & 63, quad = lane >> 4, l16 = lane & 15;
  const int bw = blockIdx.x;
  const int b = bw >> 6, win = bw & 63, wy = win >> 3, wx = win & 7;

  bf16x8 zf;
#pragma unroll
  for (int i = 0; i < 8; ++i) zf[i] = (__bf16)0.0f;
  const floatx4 zz = {0.f, 0.f, 0.f, 0.f};

  for (int c = tid; c < 2352; c += 256) {
    int r = c / 48, c8 = c - r * 48;
    int py = (r * 37) >> 8, px = r - py * 7;
    int hh = wy * 7 + py + 3; if (hh >= 56) hh -= 56;
    int wc = wx * 7 + px + 3; if (wc >= 56) wc -= 56;
    *(bf16x8*)&lds[XW + r * 392 + c8 * 8] =
        cvt8(x + (size_t)((b * 56 + hh) * 56 + wc) * 384 + c8 * 8);
  }
  __syncthreads();

  int yj[4], xj[4], ccv[4];
#pragma unroll
  for (int nt = 0; nt < 4; ++nt) {
    int j = nt * 16 + l16;
    int y = (j * 37) >> 8, xx = j - y * 7;
    yj[nt] = y; xj[nt] = xx;
    ccv[nt] = reg3(wy * 7 + y) * 3 + reg3(wx * 7 + xx);
  }

  for (int g = 0; g < 3; ++g) {
    const int hme = g * 4 + wave;
    const float* bp[6];
    int wrowv[6];
#pragma unroll
    for (int nt = 0; nt < 6; ++nt) {
      int which = nt >> 1;
      int n32 = (nt & 1) * 16 + l16;
      int wrow = which * 384 + hme * 32 + n32;
      wrowv[nt] = wrow;
      bp[nt] = w + (size_t)wrow * 384 + quad * 8;
    }

    floatx4 acc[4][6];
#pragma unroll
    for (int mt = 0; mt < 4; ++mt)
#pragma unroll
      for (int nt = 0; nt < 6; ++nt) acc[mt][nt] = zz;

    for (int ks = 0; ks < 12; ++ks) {
      bf16x8 af[4];
#pragma unroll
      for (int mt = 0; mt < 4; ++mt) {
        int am = mt * 16 + l16;
        af[mt] = (am < 49) ? *(const bf16x8*)&lds[XW + am * 392 + ks * 32 + quad * 8] : zf;
      }
#pragma unroll
      for (int nt = 0; nt < 6; ++nt) {
        bf16x8 bfr = cvt8(bp[nt] + ks * 32);
#pragma unroll
        for (int mt = 0; mt < 4; ++mt)
          acc[mt][nt] = __builtin_amdgcn_mfma_f32_16x16x32_bf16(af[mt], bfr, acc[mt][nt], 0, 0, 0);
      }
    }

    for (int hh2 = 0; hh2 < 4; ++hh2) {
      const int h = g * 4 + hh2;
      __syncthreads();
      if (wave == hh2) {
        float bb[6];
#pragma unroll
        for (int nt = 0; nt < 6; ++nt) bb[nt] = qkvb[wrowv[nt]];
#pragma unroll
        for (int mt = 0; mt < 4; ++mt) {
#pragma unroll
          for (int r = 0; r < 4; ++r) {
            int token = mt * 16 + quad * 4 + r;
#pragma unroll
            for (int nt = 0; nt < 6; ++nt) {
              float val = acc[mt][nt][r] + bb[nt];
              int n32 = (nt & 1) * 16 + l16;
              if (nt < 2)
                lds[QO + token * 40 + n32] = f2bf(val * 0.17677669529663687f);
              else if (nt < 4)
                lds[KO + token * 40 + n32] = f2bf(val);
              else
                lds[VT + n32 * 72 + token] = f2bf(val);
            }
          }
        }
      }
      __syncthreads();

      bf16x8 aq = *(const bf16x8*)&lds[QO + (wave * 16 + l16) * 40 + quad * 8];
      bf16x8 bk[4];
#pragma unroll
      for (int nt = 0; nt < 4; ++nt)
        bk[nt] = *(const bf16x8*)&lds[KO + (nt * 16 + l16) * 40 + quad * 8];
      bf16x8 bv[2][2];
#pragma unroll
      for (int nt = 0; nt < 2; ++nt)
#pragma unroll
        for (int ks = 0; ks < 2; ++ks)
          bv[nt][ks] = *(const bf16x8*)&lds[VT + (nt * 16 + l16) * 72 + ks * 32 + quad * 8];
      __syncthreads();

      floatx4 s4[4];
#pragma unroll
      for (int nt = 0; nt < 4; ++nt)
        s4[nt] = __builtin_amdgcn_mfma_f32_16x16x32_bf16(aq, bk[nt], zz, 0, 0, 0);

      const float NEG = -1e30f;
#pragma unroll
      for (int r = 0; r < 4; ++r) {
        int i = wave * 16 + quad * 4 + r;
        int yi = (i * 37) >> 8, xi = i - yi * 7;
        int rc = reg3(wy * 7 + yi) * 3 + reg3(wx * 7 + xi);
        bool rowok = (i < 49);
        float vals[4];
        float mx = NEG;
#pragma unroll
        for (int nt = 0; nt < 4; ++nt) {
          int j = nt * 16 + l16;
          float v = s4[nt][r];
          if (rowok && j < 49) {
            v += table[((yi - yj[nt] + 6) * 13 + (xi - xj[nt] + 6)) * 12 + h];
            if (rc != ccv[nt]) v -= 100.0f;
          } else {
            v = NEG;
          }
          vals[nt] = v;
          mx = fmaxf(mx, v);
        }
#pragma unroll
        for (int off = 1; off < 16; off <<= 1)
          mx = fmaxf(mx, __shfl_xor(mx, off, 64));
        float sum = 0.f;
#pragma unroll
        for (int nt = 0; nt < 4; ++nt) {
          float e = __expf(vals[nt] - mx);
          vals[nt] = e;
          sum += e;
        }
#pragma unroll
        for (int off = 1; off < 16; off <<= 1) sum += __shfl_xor(sum, off, 64);
        float rinv = 1.f / sum;
#pragma unroll
        for (int nt = 0; nt < 4; ++nt)
          lds[PO + i * 72 + nt * 16 + l16] = f2bf(vals[nt] * rinv);
      }
      __syncthreads();

      bf16x8 ap[2];
#pragma unroll
      for (int ks = 0; ks < 2; ++ks)
        ap[ks] = *(const bf16x8*)&lds[PO + (wave * 16 + l16) * 72 + ks * 32 + quad * 8];
      floatx4 o2[2] = {zz, zz};
#pragma unroll
      for (int ks = 0; ks < 2; ++ks)
#pragma unroll
        for (int nt = 0; nt < 2; ++nt)
          o2[nt] = __builtin_amdgcn_mfma_f32_16x16x32_bf16(ap[ks], bv[nt][ks], o2[nt], 0, 0, 0);

#pragma unroll
      for (int r = 0; r < 4; ++r) {
        int i = wave * 16 + quad * 4 + r;
        if (i < 49) {
          int py = (i * 37) >> 8, px = i - py * 7;
          int hh = wy * 7 + py + 3; if (hh >= 56) hh -= 56;
          int wc = wx * 7 + px + 3; if (wc >= 56) wc -= 56;
          size_t base = (size_t)((b * 56 + hh) * 56 + wc) * 384 + h * 32;
#pragma unroll
          for (int nt = 0; nt < 2; ++nt)
            out[base + nt * 16 + l16] = o2[nt][r];
        }
      }
    }
  }
}

__global__ __launch_bounds__(256) void proj_inplace(
    float* __restrict__ out, const float* __restrict__ w,
    const float* __restrict__ pb) {
  __shared__ unsigned short A[64 * 392];
  const int tid = threadIdx.x;
  const int wave = tid >> 6, lane = tid & 63, quad = lane >> 4, l16 = lane & 15;
  const int tm = blockIdx.x;

  for (int c = tid; c < 3072; c += 256) {
    int r = c / 48, c8 = c - r * 48;
    *(bf16x8*)&A[r * 392 + c8 * 8] = cvt8(out + (size_t)(tm * 64 + r) * 384 + c8 * 8);
  }
  __syncthreads();

  const float* bp[6];
#pragma unroll
  for (int nt = 0; nt < 6; ++nt)
    bp[nt] = w + (size_t)(wave * 96 + nt * 16 + l16) * 384 + quad * 8;

  const floatx4 zz = {0.f, 0.f, 0.f, 0.f};
  floatx4 acc[4][6];
#pragma unroll
  for (int mt = 0; mt < 4; ++mt)
#pragma unroll
    for (int nt = 0; nt < 6; ++nt) acc[mt][nt] = zz;

  for (int ks = 0; ks < 12; ++ks) {
    bf16x8 af[4];
#pragma unroll
    for (int mt = 0; mt < 4; ++mt)
      af[mt] = *(const bf16x8*)&A[(mt * 16 + l16) * 392 + ks * 32 + quad * 8];
#pragma unroll
    for (int nt = 0; nt < 6; ++nt) {
      bf16x8 bfr = cvt8(bp[nt] + ks * 32);
#pragma unroll
      for (int mt = 0; mt < 4; ++mt)
        acc[mt][nt] = __builtin_amdgcn_mfma_f32_16x16x32_bf16(af[mt], bfr, acc[mt][nt], 0, 0, 0);
    }
  }

#pragma unroll
  for (int mt = 0; mt < 4; ++mt) {
#pragma unroll
    for (int r = 0; r < 4; ++r) {
      int t = tm * 64 + mt * 16 + quad * 4 + r;
#pragma unroll
      for (int nt = 0; nt < 6; ++nt) {
        int col = wave * 96 + nt * 16 + l16;
        out[(size_t)t * 384 + col] = acc[mt][nt][r] + pb[col];
      }
    }
  }
}

extern "C" void kernel_launch(void* const* d_in, const int* in_sizes, int n_in,
                              void* d_out, int out_size, void* d_ws, size_t ws_size,
                              hipStream_t stream) {
  const float* x      = (const float*)d_in[0];
  const float* qkv_w  = (const float*)d_in[1];
  const float* qkv_b  = (const float*)d_in[2];
  const float* proj_w = (const float*)d_in[3];
  const float* proj_b = (const float*)d_in[4];
  const float* table  = (const float*)d_in[5];
  float* out = (float*)d_out;

  const size_t NEED = (size_t)(NX + NQW + NPW + NX + NX) * 2;  // 116,785,152 B
  if (ws_size >= NEED) {
    unsigned short* xb  = (unsigned short*)d_ws;  // region unused now
    unsigned short* wqb = xb + NX;
    unsigned short* wpb = wqb + NQW;
    unsigned short* vb  = wpb + NPW;
    unsigned short* ob  = vb + NX;
    unsigned short* qkb = (unsigned short*)d_out;  // q+k scratch fills d_out exactly

    cvt_w<<<288, 256, 0, stream>>>(qkv_w, proj_w, wqb, wpb);
    qkv_gemm<<<784, 256, 0, stream>>>(x, wqb, qkv_b, qkb, vb);
    attn<<<3072, 256, 0, stream>>>(qkb, vb, table, ob);
    proj_gemm<<<784, 256, 0, stream>>>(ob, wpb, proj_b, out);
  } else {
    swin_fused<<<1024, 256, 0, stream>>>(x, qkv_w, qkv_b, table, out);
    proj_inplace<<<784, 256, 0, stream>>>(out, proj_w, proj_b);
  }
}